// Round 8
// baseline (560.628 us; speedup 1.0000x reference)
//
#include <hip/hip_runtime.h>

// CombinedBandPassFilter as i8-MFMA fixed-point GEMM:
//   out[b,band,t] = sum_k H[band,k] * x[b, t+k-384]
// x -> i16 (x*4096), h -> i16 (h*Sh_band, pow2), each split into i8 hi/lo:
//   x_f*h_f = 65536*xh.hh + 256*(xh.hl + xl.hh) + xl.hl(dropped, ~1e-4)
// mfma_i32_16x16x64_i8 (K=64, 1.9x bf16 rate), exact i32 accumulation.
// Round-8 (= round-7 resubmitted after infra timeout): R6 structure
// (pre-packed A, reg-dbuf, BN=256, barrier-free loop), 13 K-steps of 64
// taps, 3 MFMAs/step/(q,mt) into accHi/accMid.

typedef __attribute__((ext_vector_type(4))) int i32x4;

#define T_LEN   32768
#define BATCH   32
#define NBANDS  40
#define KROW    769
#define NSTEP   13             // 13*64 = 832 padded taps
#define PADL    384
#define NTILES  128            // 256-wide time tiles per batch
#define CP      1200           // byte stride per shifted copy (1200%128=48, %8=0)
#define WIN     1088           // bytes staged per copy (max used idx 1086)
#define SXF     4096.0f

union frag { uint4 v; i32x4 i4; unsigned u[4]; };

// ---- prep 1: per-band pow-2 scale Sh and epilogue factor 1/(4096*Sh) ----
__global__ void scale_filters(const float* __restrict__ kern,
                              float* __restrict__ Sh, float* __restrict__ fb) {
    const int band = blockIdx.x;           // 0..47
    const int tid = threadIdx.x;
    if (band >= NBANDS) {
        if (tid == 0) { Sh[band] = 1.f; fb[band] = 0.f; }
        return;
    }
    float m = 0.f;
    for (int k = tid; k < KROW; k += 64)
        m = fmaxf(m, fabsf(kern[band * KROW + k]));
    #pragma unroll
    for (int off = 32; off; off >>= 1)
        m = fmaxf(m, __shfl_down(m, off, 64));
    if (tid == 0) {
        const float s = exp2f(floorf(log2f(32600.f / m)));
        Sh[band] = s;
        fb[band] = 1.f / (SXF * s);
    }
}

// ---- prep 2: pack H into i8 MFMA A-fragments (hi/lo planes) ----
// Ahh/Ahl[(c*3+mt)*64 + lane] = 16 i8; band = mt*16+(lane&15),
// k = 64c + 16*(lane>>4) + j (j=0..15), zero-padded outside.
__global__ void pack_filters(const float* __restrict__ kern,
                             const float* __restrict__ Sh,
                             uint4* __restrict__ Ahh, uint4* __restrict__ Ahl) {
    const int blk = blockIdx.x;            // 0..38 = c*3 + mt
    const int c = blk / 3, mt = blk - 3 * c;
    const int l = threadIdx.x;
    const int band = mt * 16 + (l & 15);
    const int kb = 64 * c + 16 * (l >> 4);
    const float s = Sh[band];
    unsigned wh[4] = {0, 0, 0, 0}, wl[4] = {0, 0, 0, 0};
    #pragma unroll
    for (int j = 0; j < 16; ++j) {
        const int k = kb + j;
        const float h = (band < NBANDS && k < KROW) ? kern[band * KROW + k] : 0.f;
        const int q  = (int)rintf(h * s);
        const int lo = (int)(signed char)(q & 0xFF);
        const int hi = (q - lo) >> 8;
        wh[j >> 2] |= ((unsigned)hi & 0xFFu) << (8 * (j & 3));
        wl[j >> 2] |= ((unsigned)lo & 0xFFu) << (8 * (j & 3));
    }
    Ahh[blk * 64 + l] = make_uint4(wh[0], wh[1], wh[2], wh[3]);
    Ahl[blk * 64 + l] = make_uint4(wl[0], wl[1], wl[2], wl[3]);
}

__global__ __launch_bounds__(256, 4)
void conv_mfma_i8(const float* __restrict__ x,
                  const uint4* __restrict__ Ahh, const uint4* __restrict__ Ahl,
                  const float* __restrict__ fb, float* __restrict__ out) {
    __shared__ signed char xhs[8 * CP];    // 8 byte-shifted hi-plane copies
    __shared__ signed char xls[8 * CP];    // 8 byte-shifted lo-plane copies
    __shared__ float fs[48];

    const int tid  = threadIdx.x;
    const int bx   = blockIdx.x;
    const int b    = bx >> 7;
    const int tile = bx & (NTILES - 1);
    const int t0   = tile << 8;
    const float* xb = x + (size_t)b * T_LEN;
    const bool interior = (tile >= 2) && (tile <= 125);

    if (tid < 48) fs[tid] = fb[tid];

    // ---- stage x: quantize to i16, split i8 hi/lo, 8 shifted copies ----
    for (int ci = tid; ci < 8 * 136; ci += 256) {
        const int s = ci & 7, m = ci >> 3;
        const int gbase = t0 - PADL + 8 * m + s;   // copy_s[8m..8m+8) = w[8m+s..]
        float v[8];
        if (interior) {
            #pragma unroll
            for (int j = 0; j < 8; ++j) v[j] = xb[gbase + j];
        } else {
            #pragma unroll
            for (int j = 0; j < 8; ++j) {
                const int g = gbase + j;
                v[j] = (g >= 0 && g < T_LEN) ? xb[g] : 0.f;
            }
        }
        unsigned wh0 = 0, wh1 = 0, wl0 = 0, wl1 = 0;
        #pragma unroll
        for (int j = 0; j < 8; ++j) {
            const int vi = (int)rintf(fminf(fmaxf(v[j] * SXF, -32600.f), 32600.f));
            const int lo = (int)(signed char)(vi & 0xFF);
            const int hi = (vi - lo) >> 8;
            if (j < 4) {
                wh0 |= ((unsigned)hi & 0xFFu) << (8 * j);
                wl0 |= ((unsigned)lo & 0xFFu) << (8 * j);
            } else {
                wh1 |= ((unsigned)hi & 0xFFu) << (8 * (j - 4));
                wl1 |= ((unsigned)lo & 0xFFu) << (8 * (j - 4));
            }
        }
        *(uint2*)(xhs + s * CP + 8 * m) = make_uint2(wh0, wh1);
        *(uint2*)(xls + s * CP + 8 * m) = make_uint2(wl0, wl1);
    }
    __syncthreads();

    const int wave = tid >> 6, l = tid & 63;
    const int nl = l & 15, gl = l >> 4;
    const int s8 = nl & 7;

    int off[4];                            // aligned byte offsets per q
    #pragma unroll
    for (int q = 0; q < 4; ++q)
        off[q] = s8 * CP + ((wave * 4 + q) * 16 + nl - s8) + 16 * gl;

    i32x4 accHi[4][3], accMid[4][3];
    #pragma unroll
    for (int q = 0; q < 4; ++q)
        #pragma unroll
        for (int mt = 0; mt < 3; ++mt) {
            accHi[q][mt]  = (i32x4){0, 0, 0, 0};
            accMid[q][mt] = (i32x4){0, 0, 0, 0};
        }

    const uint4* Ahh4 = Ahh + l;
    const uint4* Ahl4 = Ahl + l;
    frag hh0[3], hl0[3], hh1[3], hl1[3];

#define LOAD_A(dh, dl, step)                                        \
    {   _Pragma("unroll")                                           \
        for (int mt = 0; mt < 3; ++mt) {                            \
            dh[mt].v = Ahh4[((step) * 3 + mt) * 64];                \
            dl[mt].v = Ahl4[((step) * 3 + mt) * 64];                \
        }                                                           \
    }
#define DO_STEP(step, fhh, fhl)                                     \
    {   _Pragma("unroll")                                           \
        for (int q = 0; q < 4; ++q) {                               \
            const int base = off[q] + 64 * (step);                  \
            const uint2 a0 = *(const uint2*)(xhs + base);           \
            const uint2 a1 = *(const uint2*)(xhs + base + 8);       \
            const uint2 c0 = *(const uint2*)(xls + base);           \
            const uint2 c1 = *(const uint2*)(xls + base + 8);       \
            frag bxh, bxl;                                          \
            bxh.u[0] = a0.x; bxh.u[1] = a0.y;                       \
            bxh.u[2] = a1.x; bxh.u[3] = a1.y;                       \
            bxl.u[0] = c0.x; bxl.u[1] = c0.y;                       \
            bxl.u[2] = c1.x; bxl.u[3] = c1.y;                       \
            _Pragma("unroll")                                       \
            for (int mt = 0; mt < 3; ++mt) {                        \
                accHi[q][mt] = __builtin_amdgcn_mfma_i32_16x16x64_i8( \
                    fhh[mt].i4, bxh.i4, accHi[q][mt], 0, 0, 0);     \
                accMid[q][mt] = __builtin_amdgcn_mfma_i32_16x16x64_i8( \
                    fhl[mt].i4, bxh.i4, accMid[q][mt], 0, 0, 0);    \
                accMid[q][mt] = __builtin_amdgcn_mfma_i32_16x16x64_i8( \
                    fhh[mt].i4, bxl.i4, accMid[q][mt], 0, 0, 0);    \
            }                                                       \
        }                                                           \
    }

    LOAD_A(hh0, hl0, 0);
    for (int c = 0; c < NSTEP - 1; c += 2) {       // c = 0,2,...,10
        LOAD_A(hh1, hl1, c + 1);
        DO_STEP(c, hh0, hl0);
        LOAD_A(hh0, hl0, c + 2);                   // c+2 <= 12
        DO_STEP(c + 1, hh1, hl1);
    }
    DO_STEP(NSTEP - 1, hh0, hl0);                  // step 12 (taps 768..831)
#undef LOAD_A
#undef DO_STEP

    // ---- epilogue: C/D col = lane&15 (=t), row = (lane>>4)*4 + rr (=band) ----
    #pragma unroll
    for (int q = 0; q < 4; ++q) {
        const int t = t0 + (wave * 4 + q) * 16 + nl;
        #pragma unroll
        for (int mt = 0; mt < 3; ++mt)
            #pragma unroll
            for (int rr = 0; rr < 4; ++rr) {
                const int band = mt * 16 + gl * 4 + rr;
                if (band < NBANDS) {
                    const float vv = (float)accHi[q][mt][rr] * 65536.f
                                   + (float)accMid[q][mt][rr] * 256.f;
                    out[((size_t)b * NBANDS + band) * T_LEN + t] = vv * fs[band];
                }
            }
    }
}

extern "C" void kernel_launch(void* const* d_in, const int* in_sizes, int n_in,
                              void* d_out, int out_size, void* d_ws, size_t ws_size,
                              hipStream_t stream) {
    const float* x    = (const float*)d_in[0];
    const float* kern = (const float*)d_in[1];
    float* out        = (float*)d_out;
    // ws layout: Ahh[39*64 uint4] | Ahl[39*64 uint4] | Sh[48] | fb[48]
    uint4* Ahh = (uint4*)d_ws;
    uint4* Ahl = Ahh + 39 * 64;
    float* Sh  = (float*)(Ahl + 39 * 64);
    float* fb  = Sh + 48;
    scale_filters<<<48, 64, 0, stream>>>(kern, Sh, fb);
    pack_filters<<<39, 64, 0, stream>>>(kern, Sh, Ahh, Ahl);
    conv_mfma_i8<<<BATCH * NTILES, 256, 0, stream>>>(x, Ahh, Ahl, fb, out);
}

// Round 10
// 253.967 us; speedup vs baseline: 2.2075x; 2.2075x over previous
//
#include <hip/hip_runtime.h>

// CombinedBandPassFilter as i8-MFMA fixed-point GEMM:
//   out[b,band,t] = sum_k H[band,k] * x[b, t+k-384]
// x -> i16 (x*4096), h -> i16 (h*Sh_band, pow2), each split into i8 hi/lo:
//   x_f*h_f = 65536*xh.hh + 256*(xh.hl + xl.hh) + xl.hl(dropped, ~1e-4)
// mfma_i32_16x16x64_i8 (K=64, ~1.9x bf16 rate), exact i32 accumulation.
//
// Round-10 (= round-9 resubmitted after infra timeout): identical to round-8
// EXCEPT __launch_bounds__(256, 2).
// R8 failure: (256,4) capped unified VGPR+AGPR at 128/wave; acc(96)+Adbuf(48)
// +B+addr ~170 -> accumulators spilled to scratch (FETCH 515MB, WRITE 1.45GB,
// MfmaUtil 12%). (256,2) gives 256-reg budget: no spill, 2 waves/SIMD (the
// HK-GEMM occupancy regime); 24 independent acc chains provide the ILP.

typedef __attribute__((ext_vector_type(4))) int i32x4;

#define T_LEN   32768
#define BATCH   32
#define NBANDS  40
#define KROW    769
#define NSTEP   13             // 13*64 = 832 padded taps
#define PADL    384
#define NTILES  128            // 256-wide time tiles per batch
#define CP      1200           // byte stride per shifted copy (1200%128=48, %8=0)
#define SXF     4096.0f

union frag { uint4 v; i32x4 i4; unsigned u[4]; };

// ---- prep 1: per-band pow-2 scale Sh and epilogue factor 1/(4096*Sh) ----
__global__ void scale_filters(const float* __restrict__ kern,
                              float* __restrict__ Sh, float* __restrict__ fb) {
    const int band = blockIdx.x;           // 0..47
    const int tid = threadIdx.x;
    if (band >= NBANDS) {
        if (tid == 0) { Sh[band] = 1.f; fb[band] = 0.f; }
        return;
    }
    float m = 0.f;
    for (int k = tid; k < KROW; k += 64)
        m = fmaxf(m, fabsf(kern[band * KROW + k]));
    #pragma unroll
    for (int off = 32; off; off >>= 1)
        m = fmaxf(m, __shfl_down(m, off, 64));
    if (tid == 0) {
        const float s = exp2f(floorf(log2f(32600.f / m)));
        Sh[band] = s;
        fb[band] = 1.f / (SXF * s);
    }
}

// ---- prep 2: pack H into i8 MFMA A-fragments (hi/lo planes) ----
// Ahh/Ahl[(c*3+mt)*64 + lane] = 16 i8; band = mt*16+(lane&15),
// k = 64c + 16*(lane>>4) + j (j=0..15), zero-padded outside.
__global__ void pack_filters(const float* __restrict__ kern,
                             const float* __restrict__ Sh,
                             uint4* __restrict__ Ahh, uint4* __restrict__ Ahl) {
    const int blk = blockIdx.x;            // 0..38 = c*3 + mt
    const int c = blk / 3, mt = blk - 3 * c;
    const int l = threadIdx.x;
    const int band = mt * 16 + (l & 15);
    const int kb = 64 * c + 16 * (l >> 4);
    const float s = Sh[band];
    unsigned wh[4] = {0, 0, 0, 0}, wl[4] = {0, 0, 0, 0};
    #pragma unroll
    for (int j = 0; j < 16; ++j) {
        const int k = kb + j;
        const float h = (band < NBANDS && k < KROW) ? kern[band * KROW + k] : 0.f;
        const int q  = (int)rintf(h * s);
        const int lo = (int)(signed char)(q & 0xFF);
        const int hi = (q - lo) >> 8;
        wh[j >> 2] |= ((unsigned)hi & 0xFFu) << (8 * (j & 3));
        wl[j >> 2] |= ((unsigned)lo & 0xFFu) << (8 * (j & 3));
    }
    Ahh[blk * 64 + l] = make_uint4(wh[0], wh[1], wh[2], wh[3]);
    Ahl[blk * 64 + l] = make_uint4(wl[0], wl[1], wl[2], wl[3]);
}

__global__ __launch_bounds__(256, 2)
void conv_mfma_i8(const float* __restrict__ x,
                  const uint4* __restrict__ Ahh, const uint4* __restrict__ Ahl,
                  const float* __restrict__ fb, float* __restrict__ out) {
    __shared__ signed char xhs[8 * CP];    // 8 byte-shifted hi-plane copies
    __shared__ signed char xls[8 * CP];    // 8 byte-shifted lo-plane copies
    __shared__ float fs[48];

    const int tid  = threadIdx.x;
    const int bx   = blockIdx.x;
    const int b    = bx >> 7;
    const int tile = bx & (NTILES - 1);
    const int t0   = tile << 8;
    const float* xb = x + (size_t)b * T_LEN;
    const bool interior = (tile >= 2) && (tile <= 125);

    if (tid < 48) fs[tid] = fb[tid];

    // ---- stage x: quantize to i16, split i8 hi/lo, 8 shifted copies ----
    for (int ci = tid; ci < 8 * 136; ci += 256) {
        const int s = ci & 7, m = ci >> 3;
        const int gbase = t0 - PADL + 8 * m + s;   // copy_s[8m..8m+8) = w[8m+s..]
        float v[8];
        if (interior) {
            #pragma unroll
            for (int j = 0; j < 8; ++j) v[j] = xb[gbase + j];
        } else {
            #pragma unroll
            for (int j = 0; j < 8; ++j) {
                const int g = gbase + j;
                v[j] = (g >= 0 && g < T_LEN) ? xb[g] : 0.f;
            }
        }
        unsigned wh0 = 0, wh1 = 0, wl0 = 0, wl1 = 0;
        #pragma unroll
        for (int j = 0; j < 8; ++j) {
            const int vi = (int)rintf(fminf(fmaxf(v[j] * SXF, -32600.f), 32600.f));
            const int lo = (int)(signed char)(vi & 0xFF);
            const int hi = (vi - lo) >> 8;
            if (j < 4) {
                wh0 |= ((unsigned)hi & 0xFFu) << (8 * j);
                wl0 |= ((unsigned)lo & 0xFFu) << (8 * j);
            } else {
                wh1 |= ((unsigned)hi & 0xFFu) << (8 * (j - 4));
                wl1 |= ((unsigned)lo & 0xFFu) << (8 * (j - 4));
            }
        }
        *(uint2*)(xhs + s * CP + 8 * m) = make_uint2(wh0, wh1);
        *(uint2*)(xls + s * CP + 8 * m) = make_uint2(wl0, wl1);
    }
    __syncthreads();

    const int wave = tid >> 6, l = tid & 63;
    const int nl = l & 15, gl = l >> 4;
    const int s8 = nl & 7;

    int off[4];                            // aligned byte offsets per q
    #pragma unroll
    for (int q = 0; q < 4; ++q)
        off[q] = s8 * CP + ((wave * 4 + q) * 16 + nl - s8) + 16 * gl;

    i32x4 accHi[4][3], accMid[4][3];
    #pragma unroll
    for (int q = 0; q < 4; ++q)
        #pragma unroll
        for (int mt = 0; mt < 3; ++mt) {
            accHi[q][mt]  = (i32x4){0, 0, 0, 0};
            accMid[q][mt] = (i32x4){0, 0, 0, 0};
        }

    const uint4* Ahh4 = Ahh + l;
    const uint4* Ahl4 = Ahl + l;
    frag hh0[3], hl0[3], hh1[3], hl1[3];

#define LOAD_A(dh, dl, step)                                        \
    {   _Pragma("unroll")                                           \
        for (int mt = 0; mt < 3; ++mt) {                            \
            dh[mt].v = Ahh4[((step) * 3 + mt) * 64];                \
            dl[mt].v = Ahl4[((step) * 3 + mt) * 64];                \
        }                                                           \
    }
#define DO_STEP(step, fhh, fhl)                                     \
    {   _Pragma("unroll")                                           \
        for (int q = 0; q < 4; ++q) {                               \
            const int base = off[q] + 64 * (step);                  \
            const uint2 a0 = *(const uint2*)(xhs + base);           \
            const uint2 a1 = *(const uint2*)(xhs + base + 8);       \
            const uint2 c0 = *(const uint2*)(xls + base);           \
            const uint2 c1 = *(const uint2*)(xls + base + 8);       \
            frag bxh, bxl;                                          \
            bxh.u[0] = a0.x; bxh.u[1] = a0.y;                       \
            bxh.u[2] = a1.x; bxh.u[3] = a1.y;                       \
            bxl.u[0] = c0.x; bxl.u[1] = c0.y;                       \
            bxl.u[2] = c1.x; bxl.u[3] = c1.y;                       \
            _Pragma("unroll")                                       \
            for (int mt = 0; mt < 3; ++mt) {                        \
                accHi[q][mt] = __builtin_amdgcn_mfma_i32_16x16x64_i8( \
                    fhh[mt].i4, bxh.i4, accHi[q][mt], 0, 0, 0);     \
                accMid[q][mt] = __builtin_amdgcn_mfma_i32_16x16x64_i8( \
                    fhl[mt].i4, bxh.i4, accMid[q][mt], 0, 0, 0);    \
                accMid[q][mt] = __builtin_amdgcn_mfma_i32_16x16x64_i8( \
                    fhh[mt].i4, bxl.i4, accMid[q][mt], 0, 0, 0);    \
            }                                                       \
        }                                                           \
    }

    LOAD_A(hh0, hl0, 0);
    for (int c = 0; c < NSTEP - 1; c += 2) {       // c = 0,2,...,10
        LOAD_A(hh1, hl1, c + 1);
        DO_STEP(c, hh0, hl0);
        LOAD_A(hh0, hl0, c + 2);                   // c+2 <= 12
        DO_STEP(c + 1, hh1, hl1);
    }
    DO_STEP(NSTEP - 1, hh0, hl0);                  // step 12 (taps 768..831)
#undef LOAD_A
#undef DO_STEP

    // ---- epilogue: C/D col = lane&15 (=t), row = (lane>>4)*4 + rr (=band) ----
    #pragma unroll
    for (int q = 0; q < 4; ++q) {
        const int t = t0 + (wave * 4 + q) * 16 + nl;
        #pragma unroll
        for (int mt = 0; mt < 3; ++mt)
            #pragma unroll
            for (int rr = 0; rr < 4; ++rr) {
                const int band = mt * 16 + gl * 4 + rr;
                if (band < NBANDS) {
                    const float vv = (float)accHi[q][mt][rr] * 65536.f
                                   + (float)accMid[q][mt][rr] * 256.f;
                    out[((size_t)b * NBANDS + band) * T_LEN + t] = vv * fs[band];
                }
            }
    }
}

extern "C" void kernel_launch(void* const* d_in, const int* in_sizes, int n_in,
                              void* d_out, int out_size, void* d_ws, size_t ws_size,
                              hipStream_t stream) {
    const float* x    = (const float*)d_in[0];
    const float* kern = (const float*)d_in[1];
    float* out        = (float*)d_out;
    // ws layout: Ahh[39*64 uint4] | Ahl[39*64 uint4] | Sh[48] | fb[48]
    uint4* Ahh = (uint4*)d_ws;
    uint4* Ahl = Ahh + 39 * 64;
    float* Sh  = (float*)(Ahl + 39 * 64);
    float* fb  = Sh + 48;
    scale_filters<<<48, 64, 0, stream>>>(kern, Sh, fb);
    pack_filters<<<39, 64, 0, stream>>>(kern, Sh, Ahh, Ahl);
    conv_mfma_i8<<<BATCH * NTILES, 256, 0, stream>>>(x, Ahh, Ahl, fb, out);
}